// Round 9
// baseline (129.516 us; speedup 1.0000x reference)
//
#include <hip/hip_runtime.h>
#include <hip/hip_bf16.h>
#include <stdint.h>

// Problem constants (LinearRNN): B=16, T=4096, D_IN=256, HID=512, D_OUT=256
#define BATCH 16
#define SEQT  4096
#define DIN   256
#define HID   512
#define DOUT  256
#define M_TOT 65536
#define CLEN  128                 // chunk length (== GEMM m-tile)
#define NCHUNK 32                 // SEQT / CLEN

typedef short bf16x8 __attribute__((ext_vector_type(8)));
typedef float f32x4  __attribute__((ext_vector_type(4)));
typedef unsigned short u16;
typedef unsigned short u16x4 __attribute__((ext_vector_type(4)));
typedef unsigned int uint32;

// async global->LDS, 16B per lane; LDS dest is wave-uniform base + lane*16
__device__ __forceinline__ void ld_lds16(const void* g, void* l) {
    __builtin_amdgcn_global_load_lds(
        (const __attribute__((address_space(1))) void*)g,
        (__attribute__((address_space(3))) void*)l, 16, 0, 0);
}

__device__ __forceinline__ u16 f2bf_rne(float f) {
    uint32 v = __float_as_uint(f);
    v += 0x7FFFu + ((v >> 16) & 1u);
    return (u16)(v >> 16);
}

__device__ __forceinline__ float bf2f(u16 s) {
    return __uint_as_float((uint32)s << 16);
}

// trunc-hi / rne-lo split: f ~= hi + lo, ~17-bit combined mantissa
__device__ __forceinline__ void splitf(float f, u16& hi, u16& lo) {
    const uint32 u = __float_as_uint(f);
    hi = (u16)(u >> 16);
    lo = f2bf_rne(f - __uint_as_float(u & 0xFFFF0000u));
}

// ---------------------------------------------------------------------------
// prep: block 0 -> wdiag + wpow (w^(tl+1), tl<128); blocks 1..128 -> W_in
// split; blocks 129..256 -> W_out split.
// ---------------------------------------------------------------------------
__global__ __launch_bounds__(256) void prep(
        const float* __restrict__ Wh, const float* __restrict__ Win,
        const float* __restrict__ Wout, float* __restrict__ wdiag,
        float* __restrict__ wpow, u16* __restrict__ Winhi,
        u16* __restrict__ Winlo, u16* __restrict__ Wouthi,
        u16* __restrict__ Woutlo) {
    const int bid = blockIdx.x, tid = threadIdx.x;
    if (bid == 0) {
        for (int h = tid; h < HID; h += 256) {
            const float wv = Wh[(size_t)h * HID + h];
            wdiag[h] = wv;
            float p = 1.f;
            for (int t = 0; t < CLEN; ++t) { p *= wv; wpow[t * HID + h] = p; }
        }
    } else if (bid <= 128) {
        const int f4 = (bid - 1) * 256 + tid;   // < 32768
        const f32x4 v = *(const f32x4*)(Win + (size_t)f4 * 4);
        u16x4 hv, lv;
#pragma unroll
        for (int k = 0; k < 4; ++k) { u16 a, b; splitf(v[k], a, b); hv[k] = a; lv[k] = b; }
        *(u16x4*)(Winhi + (size_t)f4 * 4) = hv;
        *(u16x4*)(Winlo + (size_t)f4 * 4) = lv;
    } else {
        const int f4 = (bid - 129) * 256 + tid;
        const f32x4 v = *(const f32x4*)(Wout + (size_t)f4 * 4);
        u16x4 hv, lv;
#pragma unroll
        for (int k = 0; k < 4; ++k) { u16 a, b; splitf(v[k], a, b); hv[k] = a; lv[k] = b; }
        *(u16x4*)(Wouthi + (size_t)f4 * 4) = hv;
        *(u16x4*)(Woutlo + (size_t)f4 * 4) = lv;
    }
}

// ---------------------------------------------------------------------------
// GEMM1 + fused segmented scan, T14-pipelined:
// all staging loads are plain reg-loads issued ONE k-iter ahead (they fly
// across the barrier + MFMA phase; no vmcnt drain since no global_load_lds).
// Per iter: {split+ds_write prefetched regs; bar; issue k+1 loads; MFMA; bar}.
// Epilogue: st -> seg scan with FUSED phase2+3 (per-thread Horner carry).
// Grid: 2048 linear, XCD-swizzled.
// ---------------------------------------------------------------------------
__global__ __launch_bounds__(256, 2) void gemm1_scan(
        const float* __restrict__ X, const u16* __restrict__ Whi,
        const u16* __restrict__ Wlo, u16* __restrict__ localbf,
        float* __restrict__ L, const float* __restrict__ wdiag,
        const float* __restrict__ wpow) {
    __shared__ __align__(16) char smem[71680];
    u16*   Ah = (u16*)smem;                 // [128][64] bf16 hi, swizzled (16KB)
    u16*   Al = (u16*)(smem + 16384);       // lo (16KB)
    u16*   Bh = (u16*)(smem + 32768);       // [128][64] bf16, swizzled (16KB)
    u16*   Bl = (u16*)(smem + 49152);       // 16KB
    float* st = (float*)smem;               // scan tile [128][132] f32 (aliased, 67.6KB)
    float* segT = (float*)(smem + 67584);   // [8][128] seg totals (4KB)

    const int tid  = threadIdx.x;
    const int w    = tid >> 6;
    const int lane = tid & 63;

    // XCD swizzle: 8 XCDs x 256 slots; slot = (m within xcd-run, n)
    const int bid  = blockIdx.x;
    const int xcd  = bid & 7;
    const int slot = bid >> 3;              // 0..255
    const int mBase = (xcd * 64 + (slot >> 2)) * 128;
    const int nBase = (slot & 3) * 128;

    const int wr = w >> 1, wc = w & 1;
    const int fr = lane & 15;
    const int kg = lane >> 4;

    const int bRow = lane >> 3;                        // row within 8-row chunk
    const int bCol = ((lane & 7) ^ bRow) * 8;          // pre-swizzled col (u16)

    f32x4 acc[4][4];
#pragma unroll
    for (int i = 0; i < 4; ++i)
#pragma unroll
        for (int j = 0; j < 4; ++j) acc[i][j] = (f32x4){0.f, 0.f, 0.f, 0.f};

    // prefetch registers (one k-iter in flight)
    f32x4 ap0[4], ap1[4];                   // A: 8 x f32x4
    bf16x8 bhp[4], blp[4];                  // B: 8 x 16B

    auto LOADK = [&](int k0) {
#pragma unroll
        for (int i = 0; i < 4; ++i) {
            const int c = w * 4 + i;
            const int r = c * 8 + bRow;
            bhp[i] = *(const bf16x8*)(Whi + (size_t)(nBase + r) * DIN + k0 + bCol);
            blp[i] = *(const bf16x8*)(Wlo + (size_t)(nBase + r) * DIN + k0 + bCol);
        }
#pragma unroll
        for (int it = 0; it < 4; ++it) {
            const int idx = it * 256 + tid;
            const int r = idx >> 3, gl = idx & 7;
            const float* src = X + (size_t)(mBase + r) * DIN + k0 + gl * 8;
            ap0[it] = *(const f32x4*)(src);
            ap1[it] = *(const f32x4*)(src + 4);
        }
    };
    auto WRITEK = [&]() {
#pragma unroll
        for (int i = 0; i < 4; ++i) {
            const int c = w * 4 + i;
            *(bf16x8*)(Bh + c * 512 + lane * 8) = bhp[i];
            *(bf16x8*)(Bl + c * 512 + lane * 8) = blp[i];
        }
#pragma unroll
        for (int it = 0; it < 4; ++it) {
            const int idx = it * 256 + tid;
            const int r = idx >> 3, gl = idx & 7;
            bf16x8 h8, l8;
#pragma unroll
            for (int e = 0; e < 4; ++e) {
                u16 a, b;
                splitf(ap0[it][e], a, b); h8[e] = (short)a; l8[e] = (short)b;
                splitf(ap1[it][e], a, b); h8[e + 4] = (short)a; l8[e + 4] = (short)b;
            }
            const int phys = r * 64 + ((gl ^ (r & 7)) * 8);
            *(bf16x8*)(Ah + phys) = h8;
            *(bf16x8*)(Al + phys) = l8;
        }
    };

    LOADK(0);
#pragma unroll
    for (int kk = 0; kk < 4; ++kk) {
        WRITEK();
        __syncthreads();
        if (kk < 3) LOADK((kk + 1) * 64);   // fly across the MFMA phase
#pragma unroll
        for (int ks = 0; ks < 2; ++ks) {
            const int colE = ks * 32 + kg * 8;
            bf16x8 ah[4], al[4], bh[4], bl[4];
#pragma unroll
            for (int f = 0; f < 4; ++f) {
                const int ra = wr * 64 + f * 16 + fr;
                const int pa = ra * 64 + (colE ^ ((fr & 7) << 3));
                ah[f] = *(const bf16x8*)(Ah + pa);
                al[f] = *(const bf16x8*)(Al + pa);
                const int rb = wc * 64 + f * 16 + fr;
                const int pb = rb * 64 + (colE ^ ((fr & 7) << 3));
                bh[f] = *(const bf16x8*)(Bh + pb);
                bl[f] = *(const bf16x8*)(Bl + pb);
            }
#pragma unroll
            for (int i = 0; i < 4; ++i)
#pragma unroll
                for (int j = 0; j < 4; ++j) {
                    acc[i][j] = __builtin_amdgcn_mfma_f32_16x16x32_bf16(ah[i], bh[j], acc[i][j], 0, 0, 0);
                    acc[i][j] = __builtin_amdgcn_mfma_f32_16x16x32_bf16(ah[i], bl[j], acc[i][j], 0, 0, 0);
                    acc[i][j] = __builtin_amdgcn_mfma_f32_16x16x32_bf16(al[i], bh[j], acc[i][j], 0, 0, 0);
                }
        }
        __syncthreads();
    }

    // epilogue: acc -> scan tile (C/D layout: col=lane&15, row=(lane>>4)*4+rg)
#pragma unroll
    for (int i = 0; i < 4; ++i)
#pragma unroll
        for (int j = 0; j < 4; ++j)
#pragma unroll
            for (int rg = 0; rg < 4; ++rg)
                st[(wr * 64 + i * 16 + kg * 4 + rg) * 132 + wc * 64 + j * 16 + fr]
                    = acc[i][j][rg];
    __syncthreads();

    // --- segmented scan along t: 8 segments of 16 rows, x4-vectorized ---
    const int sseg = tid >> 5;              // 0..7
    const int cg   = (tid & 31) * 4;        // col base within 128-col slice
    const f32x4 wv4 = *(const f32x4*)(wdiag + nBase + cg);

    // phase 1: in-register scan of one 16-row segment x 4 cols
    f32x4 rr[16];
    {
        f32x4 run = (f32x4){0.f, 0.f, 0.f, 0.f};
#pragma unroll
        for (int i = 0; i < 16; ++i) {
            const f32x4 v = *(const f32x4*)&st[(sseg * 16 + i) * 132 + cg];
#pragma unroll
            for (int e = 0; e < 4; ++e) run[e] = fmaf(wv4[e], run[e], v[e]);
            rr[i] = run;
        }
        *(f32x4*)&segT[sseg * 128 + cg] = run;
    }
    __syncthreads();

    // fused phase 2+3: every thread Horner-scans segT to get its own carry-in
    {
        const f32x4 w16 = *(const f32x4*)(wpow + 15 * HID + nBase + cg);
        f32x4 c = (f32x4){0.f, 0.f, 0.f, 0.f};
        f32x4 cin = (f32x4){0.f, 0.f, 0.f, 0.f};
#pragma unroll
        for (int s = 0; s < 8; ++s) {
            if (s == sseg) cin = c;
            const f32x4 tv = *(const f32x4*)&segT[s * 128 + cg];
#pragma unroll
            for (int e = 0; e < 4; ++e) c[e] = fmaf(w16[e], c[e], tv[e]);
        }
        if (sseg == 7) {                     // c == chunk-final state
            const int cI = (mBase >> 7) & (NCHUNK - 1);
            const int bI = mBase >> 12;
            *(f32x4*)&L[(cI * BATCH + bI) * HID + nBase + cg] = c;
        }
        // apply carry, write BF16 chunk-local state (u16x4, 8B)
        f32x4 p = wv4;                       // w^(i+1)
        u16* dst = localbf + (size_t)(mBase + sseg * 16) * HID + nBase + cg;
#pragma unroll
        for (int i = 0; i < 16; ++i) {
            u16x4 ob;
#pragma unroll
            for (int e = 0; e < 4; ++e)
                ob[e] = f2bf_rne(fmaf(p[e], cin[e], rr[i][e]));
            *(u16x4*)(dst + (size_t)i * HID) = ob;
#pragma unroll
            for (int e = 0; e < 4; ++e) p[e] *= wv4[e];
        }
    }
}

// ---------------------------------------------------------------------------
// carry across chunks: carry[c][b][h] = state entering chunk c
// ---------------------------------------------------------------------------
__global__ __launch_bounds__(256) void scan_carry(
        const float* __restrict__ L, const float* __restrict__ wpow,
        float* __restrict__ carry) {
    const int idx = blockIdx.x * 256 + threadIdx.x;   // 8192
    const int h = idx & (HID - 1);
    const int b = idx >> 9;
    const float wf = wpow[(CLEN - 1) * HID + h];      // w^128
    float H = 0.f;
    for (int c = 0; c < NCHUNK; ++c) {
        const int o = (c * BATCH + b) * HID + h;
        carry[o] = H;
        H = fmaf(wf, H, L[o]);
    }
}

// ---------------------------------------------------------------------------
// GEMM2 with fused fix: out = (local_bf16 + w^(tl+1)*carry) @ W_out^T.
// (unchanged from R8 — measured at ~5.2 TB/s, BW roofline)
// ---------------------------------------------------------------------------
__global__ __launch_bounds__(256, 2) void gemm2_fix(
        const u16* __restrict__ localbf, const u16* __restrict__ Bhi_g,
        const u16* __restrict__ Blo_g, const float* __restrict__ wpow,
        const float* __restrict__ carry, float* __restrict__ C) {
    __shared__ __align__(16) char smem[65536];
    u16* Ah = (u16*)smem;                   // [128][64] swizzled (16KB)
    u16* Al = (u16*)(smem + 16384);
    u16* Bh = (u16*)(smem + 32768);
    u16* Bl = (u16*)(smem + 49152);

    const int tid  = threadIdx.x;
    const int w    = tid >> 6;
    const int lane = tid & 63;

    const int bid  = blockIdx.x;
    const int xcd  = bid & 7;
    const int slot = bid >> 3;              // 0..127
    const int mBase = (xcd * 64 + (slot >> 1)) * 128;
    const int nBase = (slot & 1) * 128;

    const int wr = w >> 1, wc = w & 1;
    const int fr = lane & 15;
    const int kg = lane >> 4;

    const int bRow = lane >> 3;
    const int bCol = ((lane & 7) ^ bRow) * 8;

    // fix constants: whole m-tile is one (chunk, batch)
    const int cI = (mBase >> 7) & (NCHUNK - 1);
    const int bI = mBase >> 12;
    const float* crow = carry + (size_t)(cI * BATCH + bI) * HID;

    f32x4 acc[4][4];
#pragma unroll
    for (int i = 0; i < 4; ++i)
#pragma unroll
        for (int j = 0; j < 4; ++j) acc[i][j] = (f32x4){0.f, 0.f, 0.f, 0.f};

    for (int k0 = 0; k0 < HID; k0 += 64) {
        // B: async global->LDS FIRST (latency hides under A staging)
#pragma unroll
        for (int i = 0; i < 4; ++i) {
            const int c = w * 4 + i;
            const int r2 = c * 8 + bRow;
            ld_lds16(Bhi_g + (size_t)(nBase + r2) * HID + k0 + bCol, Bh + c * 512);
            ld_lds16(Blo_g + (size_t)(nBase + r2) * HID + k0 + bCol, Bl + c * 512);
        }
        // A: reg-staged, bf16 load + fix + split fused
#pragma unroll
        for (int it = 0; it < 4; ++it) {
            const int idx = it * 256 + tid;   // 0..1023 granules of 8 bf16
            const int r  = idx >> 3;          // 0..127 (tl == r)
            const int gl = idx & 7;
            const int gm = mBase + r;
            const size_t col = (size_t)(k0 + gl * 8);
            const bf16x8 lv = *(const bf16x8*)(localbf + (size_t)gm * HID + col);
            const f32x4 p0 = *(const f32x4*)(wpow + (size_t)r * HID + col);
            const f32x4 p1 = *(const f32x4*)(wpow + (size_t)r * HID + col + 4);
            const f32x4 c0 = *(const f32x4*)(crow + col);
            const f32x4 c1 = *(const f32x4*)(crow + col + 4);
            bf16x8 h8, l8;
#pragma unroll
            for (int e = 0; e < 4; ++e) {
                const float f0 = fmaf(p0[e], c0[e], bf2f((u16)lv[e]));
                const float f1 = fmaf(p1[e], c1[e], bf2f((u16)lv[e + 4]));
                u16 a, b;
                splitf(f0, a, b); h8[e] = (short)a; l8[e] = (short)b;
                splitf(f1, a, b); h8[e + 4] = (short)a; l8[e + 4] = (short)b;
            }
            const int phys = r * 64 + ((gl ^ (r & 7)) * 8);
            *(bf16x8*)(Ah + phys) = h8;
            *(bf16x8*)(Al + phys) = l8;
        }
        __syncthreads();
#pragma unroll
        for (int ks = 0; ks < 2; ++ks) {
            const int colE = ks * 32 + kg * 8;
            bf16x8 ah[4], al[4], bh[4], bl[4];
#pragma unroll
            for (int f = 0; f < 4; ++f) {
                const int ra = wr * 64 + f * 16 + fr;
                const int pa = ra * 64 + (colE ^ ((fr & 7) << 3));
                ah[f] = *(const bf16x8*)(Ah + pa);
                al[f] = *(const bf16x8*)(Al + pa);
                const int rb = wc * 64 + f * 16 + fr;
                const int pb = rb * 64 + (colE ^ ((fr & 7) << 3));
                bh[f] = *(const bf16x8*)(Bh + pb);
                bl[f] = *(const bf16x8*)(Bl + pb);
            }
#pragma unroll
            for (int i = 0; i < 4; ++i)
#pragma unroll
                for (int j = 0; j < 4; ++j) {
                    acc[i][j] = __builtin_amdgcn_mfma_f32_16x16x32_bf16(ah[i], bh[j], acc[i][j], 0, 0, 0);
                    acc[i][j] = __builtin_amdgcn_mfma_f32_16x16x32_bf16(ah[i], bl[j], acc[i][j], 0, 0, 0);
                    acc[i][j] = __builtin_amdgcn_mfma_f32_16x16x32_bf16(al[i], bh[j], acc[i][j], 0, 0, 0);
                }
        }
        __syncthreads();
    }

#pragma unroll
    for (int i = 0; i < 4; ++i) {
        const size_t row0 = (size_t)mBase + wr * 64 + i * 16 + kg * 4;
#pragma unroll
        for (int j = 0; j < 4; ++j) {
            const int col = nBase + wc * 64 + j * 16 + fr;
#pragma unroll
            for (int rg = 0; rg < 4; ++rg)
                C[(row0 + rg) * DOUT + col] = acc[i][j][rg];
        }
    }
}

// ---------------------------------------------------------------------------
extern "C" void kernel_launch(void* const* d_in, const int* in_sizes, int n_in,
                              void* d_out, int out_size, void* d_ws, size_t ws_size,
                              hipStream_t stream) {
    const float* x     = (const float*)d_in[0];   // [16,4096,256]
    const float* W_in  = (const float*)d_in[1];   // [512,256]
    const float* W_h   = (const float*)d_in[2];   // [512,512] (diagonal)
    const float* W_out = (const float*)d_in[3];   // [256,512]
    float* out = (float*)d_out;                    // [16,4096,256]

    // workspace layout
    char* ws = (char*)d_ws;
    u16*   localbf = (u16*)(ws);                       // 67,108,864 (bf16 local state)
    float* L       = (float*)(ws + 134217728);         // 1,048,576
    float* carry   = (float*)(ws + 135266304);         // 1,048,576
    float* wpow    = (float*)(ws + 136314880);         // 262,144
    float* wdiag   = (float*)(ws + 136577024);         // 2,048
    u16*   Winhi   = (u16*)(ws + 136579072);           // 262,144
    u16*   Winlo   = (u16*)(ws + 136841216);           // 262,144
    u16*   Wouthi  = (u16*)(ws + 137103360);           // 262,144
    u16*   Woutlo  = (u16*)(ws + 137365504);           // 262,144

    prep<<<257, 256, 0, stream>>>(W_h, W_in, W_out, wdiag, wpow,
                                  Winhi, Winlo, Wouthi, Woutlo);
    gemm1_scan<<<2048, 256, 0, stream>>>(x, Winhi, Winlo, localbf, L, wdiag, wpow);
    scan_carry<<<32, 256, 0, stream>>>(L, wpow, carry);
    gemm2_fix<<<1024, 256, 0, stream>>>(localbf, Wouthi, Woutlo, wpow, carry, out);
}